// Round 16
// baseline (786.984 us; speedup 1.0000x reference)
//
#include <hip/hip_runtime.h>
#include <hip/hip_bf16.h>
#include <math.h>

// Problem constants
constexpr int Bn  = 4;
constexpr int Nn  = 10000;
constexpr int En  = 320000;
constexpr int EAn = 80000;
constexpr int OUT_N = 2 * Bn * (EAn / 2);   // 320000 f32: mean | std

// ---------------------------------------------------------------------------
__global__ __launch_bounds__(256) void fill_sentinel(float* out, float v) {
    const int i = blockIdx.x * 256 + threadIdx.x;
    if (i < OUT_N) out[i] = v;
}

// ---------------------------------------------------------------------------
// Index decode (validated r8) + zero degi/cur (absorbs 2 memset launches).
// ---------------------------------------------------------------------------
__global__ __launch_bounds__(256) void decode_indices(const void* __restrict__ ei_raw,
                                                      const void* __restrict__ mask_raw,
                                                      int* __restrict__ ei32,
                                                      int* __restrict__ mask32,
                                                      int* __restrict__ degi,
                                                      int* __restrict__ cur) {
    __shared__ int is64;
    if (threadIdx.x == 0) {
        const long long* p = (const long long*)ei_raw;
        int ok = 1;
        for (int i = 0; i < 64; i++) {
            const long long v = p[i];
            if (v < 0 || v >= (long long)Nn) { ok = 0; break; }
        }
        is64 = ok;
    }
    __syncthreads();
    const int idx    = blockIdx.x * 256 + threadIdx.x;
    const int stride = gridDim.x * 256;
    if (is64) {
        for (int i = idx; i < 2 * En; i += stride)
            ei32[i] = (int)((const long long*)ei_raw)[i];
        for (int i = idx; i < EAn; i += stride)
            mask32[i] = (int)((const long long*)mask_raw)[i];
    } else {
        for (int i = idx; i < 2 * En; i += stride)
            ei32[i] = ((const int*)ei_raw)[i];
        for (int i = idx; i < EAn; i += stride)
            mask32[i] = ((const int*)mask_raw)[i];
    }
    for (int i = idx; i < Nn; i += stride) { degi[i] = 0; cur[i] = 0; }
}

// --------------------------- CSR construction (validated r10/r11) -----------
__global__ __launch_bounds__(256) void count_deg(const int* __restrict__ ei,
                                                 int* __restrict__ degi) {
    const int e = blockIdx.x * 256 + threadIdx.x;
    if (e < En) atomicAdd(&degi[ei[e]], 1);
}

// Exclusive scan via wave-shuffle (validated r15).
__global__ __launch_bounds__(256) void scan_rowstart(const int* __restrict__ degi,
                                                     int* __restrict__ row_start) {
    __shared__ int wsum[4];
    __shared__ int carry_s;
    const int tid  = threadIdx.x;
    const int lane = tid & 63;
    const int wv   = tid >> 6;
    if (tid == 0) { carry_s = 0; row_start[0] = 0; }
    __syncthreads();
    for (int t = 0; t < 40; t++) {             // 40*256 = 10240 >= Nn
        const int i = t * 256 + tid;
        int v = (i < Nn) ? degi[i] : 0;
#pragma unroll
        for (int off = 1; off < 64; off <<= 1) {
            const int x = __shfl_up(v, off);
            if (lane >= off) v += x;
        }
        if (lane == 63) wsum[wv] = v;
        __syncthreads();
        int add = 0;
        for (int w = 0; w < wv; w++) add += wsum[w];
        const int base = carry_s;
        if (i < Nn) row_start[i + 1] = base + add + v;
        __syncthreads();
        if (tid == 255) carry_s = base + add + v;
        __syncthreads();
    }
}

// rs_sorted[pos] = (r<<16)|s  (both < 2^16); eid_sorted[pos] = original edge id.
__global__ __launch_bounds__(256) void fill_csr(const int* __restrict__ ei,
                                                const int* __restrict__ row_start,
                                                int* __restrict__ cursor,
                                                unsigned int* __restrict__ rs_sorted,
                                                int* __restrict__ eid_sorted) {
    const int e = blockIdx.x * 256 + threadIdx.x;
    if (e < En) {
        const int r   = ei[e];
        const int s   = ei[En + e];
        const int pos = row_start[r] + atomicAdd(&cursor[r], 1);
        rs_sorted[pos]  = ((unsigned int)r << 16) | (unsigned int)s;
        eid_sorted[pos] = e;
    }
}

// ---------------------------------------------------------------------------
// P = X @ [Wr | Ws] -> (B*N, 256). (r13 version, kept — layer 1 only now)
// ---------------------------------------------------------------------------
template <int KX>
__global__ __launch_bounds__(256) void precompute_P(const float* __restrict__ X,
                                                    const float* __restrict__ W,
                                                    float* __restrict__ P) {
    __shared__ float xs[16 * KX];
    const int m0  = blockIdx.x * 16;
    const int tid = threadIdx.x;

    for (int idx = tid * 4; idx < 16 * KX; idx += 1024)
        *(float4*)&xs[idx] = *(const float4*)&X[(size_t)m0 * KX + idx];
    __syncthreads();

    const int col  = tid;
    const int side = col >> 7;
    const int jj   = col & 127;
    const float* Wp = W + (size_t)(side * KX) * 128 + jj;

    float acc[16];
#pragma unroll
    for (int i = 0; i < 16; i++) acc[i] = 0.f;

    for (int k = 0; k < KX; k += 4) {
        const float w0 = Wp[(size_t)(k + 0) * 128];
        const float w1 = Wp[(size_t)(k + 1) * 128];
        const float w2 = Wp[(size_t)(k + 2) * 128];
        const float w3 = Wp[(size_t)(k + 3) * 128];
#pragma unroll
        for (int i = 0; i < 16; i++) {
            const float4 x = *(const float4*)&xs[i * KX + k];
            acc[i] += x.x * w0;
            acc[i] += x.y * w1;
            acc[i] += x.z * w2;
            acc[i] += x.w * w3;
        }
    }
#pragma unroll
    for (int i = 0; i < 16; i++) P[(size_t)(m0 + i) * 256 + col] = acc[i];
}

// ---------------------------------------------------------------------------
// Edge scatter v3: batch-merged + run-hoisted P_r.
//  - One block per 32-edge window, looping all 4 batches: rs/eid/We staged
//    once (4x amortization); eattr for all batches staged in one pass.
//  - P_r loaded only at run boundaries (receiver-sorted: ~1.5 distinct r per
//    16-edge window -> ~14/16 of P_r loads were redundant). The r!=curR
//    branch is wave-uniform (all lanes share the edge sequence).
//  - Register discipline preserved (w[16] + run/curR/prv; target VGPR <= 36).
// ---------------------------------------------------------------------------
__global__ __launch_bounds__(256) void edge_scatter_sorted(const float* __restrict__ P,
                                                           const unsigned int* __restrict__ rs_sorted,
                                                           const int* __restrict__ eid_sorted,
                                                           const float* __restrict__ edge_attr,
                                                           const float* __restrict__ We,  // 16x128
                                                           const float* __restrict__ b1,
                                                           float* __restrict__ aggH) {
    __shared__ int   rc[32], sc[32], ec[32];
    __shared__ float eas[4][32 * 16];

    const int e0  = blockIdx.x * 32;
    const int tid = threadIdx.x;

    if (tid < 32) {
        const unsigned int v = rs_sorted[e0 + tid];
        rc[tid] = (int)(v >> 16);
        sc[tid] = (int)(v & 0xffffu);
        ec[tid] = eid_sorted[e0 + tid];
    }
    __syncthreads();
    // Stage eattr for ALL 4 batches: 4*32*4 = 512 float4 slots, 2 per thread.
    for (int t = tid; t < 512; t += 256) {
        const int bb = t >> 7;            // batch 0..3
        const int e  = (t >> 2) & 31;     // edge 0..31
        const int k0 = (t & 3) * 4;
        *(float4*)&eas[bb][e * 16 + k0] =
            *(const float4*)&edge_attr[(((size_t)bb * En + ec[e]) * 16) + k0];
    }
    __syncthreads();

    const int col  = tid & 127;
    const int half = tid >> 7;
    const int eb   = half * 16;

    float w[16];
#pragma unroll
    for (int k = 0; k < 16; k++) w[k] = We[k * 128 + col];
    const float b1c = b1[col];

    for (int b = 0; b < Bn; b++) {
        const float* Pb   = P + (size_t)b * Nn * 256;
        float*       aggb = aggH + (size_t)b * Nn * 128;
        const float* easb = eas[b];

        int   curR = rc[eb];
        float prv  = b1c + Pb[(size_t)curR * 256 + col];
        float run  = 0.f;
#pragma unroll 4
        for (int i = 0; i < 16; i++) {
            const int e = eb + i;
            const int r = rc[e];
            if (r != curR) {                       // wave-uniform branch
                atomicAdd(&aggb[(size_t)curR * 128 + col], run);
                run  = 0.f;
                curR = r;
                prv  = b1c + Pb[(size_t)r * 256 + col];
            }
            float a0 = prv;
            float a1 = Pb[(size_t)sc[e] * 256 + 128 + col];
            const float4 e0v = *(const float4*)&easb[e * 16 + 0];
            const float4 e1v = *(const float4*)&easb[e * 16 + 4];
            const float4 e2v = *(const float4*)&easb[e * 16 + 8];
            const float4 e3v = *(const float4*)&easb[e * 16 + 12];
            a0 += e0v.x * w[0];  a1 += e0v.y * w[1];  a0 += e0v.z * w[2];  a1 += e0v.w * w[3];
            a0 += e1v.x * w[4];  a1 += e1v.y * w[5];  a0 += e1v.z * w[6];  a1 += e1v.w * w[7];
            a0 += e2v.x * w[8];  a1 += e2v.y * w[9];  a0 += e2v.z * w[10]; a1 += e2v.w * w[11];
            a0 += e3v.x * w[12]; a1 += e3v.y * w[13]; a0 += e3v.z * w[14]; a1 += e3v.w * w[15];
            run += fmaxf(a0 + a1, 0.f);
        }
        atomicAdd(&aggb[(size_t)curR * 128 + col], run);
    }
}

// ---------------------------------------------------------------------------
// Fused node + next-stage P epilogue (validated r15).
// ---------------------------------------------------------------------------
template <int KX, bool ZERO_AGG, bool WRITE_H>
__global__ __launch_bounds__(256) void fused_node_p(const float* __restrict__ X,
                                                    float* __restrict__ aggH,
                                                    const float* __restrict__ W2,
                                                    const float* __restrict__ b2,
                                                    const int* __restrict__ row_start,
                                                    const float* __restrict__ uw,
                                                    const float* __restrict__ ub,
                                                    const float* __restrict__ Wnext, // >=256 x 128
                                                    float* __restrict__ Hout,
                                                    float* __restrict__ Pout) {
    __shared__ float ah[16 * 128];
    __shared__ float ag[16 * 128];
    __shared__ float xs[16 * KX];
    __shared__ float dg[16];

    const int m0  = blockIdx.x * 16;     // Nn % 16 == 0 -> never straddles batch
    const int tid = threadIdx.x;

    if (tid < 16) {
        const int row = m0 + tid;
        const int nl  = row - (row / Nn) * Nn;
        dg[tid] = (float)(row_start[nl + 1] - row_start[nl]);
    }
    for (int idx = tid * 4; idx < 16 * 128; idx += 1024)
        *(float4*)&ah[idx] = *(const float4*)&aggH[(size_t)m0 * 128 + idx];
    for (int idx = tid * 4; idx < 16 * KX; idx += 1024)
        *(float4*)&xs[idx] = *(const float4*)&X[(size_t)m0 * KX + idx];
    __syncthreads();

    if (ZERO_AGG) {  // own rows only; consumed into LDS above
        const float4 z = {0.f, 0.f, 0.f, 0.f};
        for (int idx = tid * 4; idx < 16 * 128; idx += 1024)
            *(float4*)&aggH[(size_t)m0 * 128 + idx] = z;
    }

    const int col  = tid & 127;
    const int half = tid >> 7;

    {   // Phase A: ag = ah @ W2 + dg*b2
        const float b2c = b2[col];
        float acc[8];
#pragma unroll
        for (int i = 0; i < 8; i++) acc[i] = dg[half * 8 + i] * b2c;
        for (int k = 0; k < 128; k += 4) {
            const float w0 = W2[(k + 0) * 128 + col];
            const float w1 = W2[(k + 1) * 128 + col];
            const float w2v = W2[(k + 2) * 128 + col];
            const float w3 = W2[(k + 3) * 128 + col];
#pragma unroll
            for (int i = 0; i < 8; i++) {
                const float4 v = *(const float4*)&ah[(half * 8 + i) * 128 + k];
                acc[i] += v.x * w0;
                acc[i] += v.y * w1;
                acc[i] += v.z * w2v;
                acc[i] += v.w * w3;
            }
        }
#pragma unroll
        for (int i = 0; i < 8; i++) ag[(half * 8 + i) * 128 + col] = acc[i];
    }
    __syncthreads();

    // Phase B: h' = relu([X | ag] @ uw + ub) -> ah (reuse) [+ global]
    {
        float acc[8];
#pragma unroll
        for (int i = 0; i < 8; i++) acc[i] = ub[col];
        for (int k = 0; k < KX; k += 4) {
            const float w0 = uw[(size_t)(k + 0) * 128 + col];
            const float w1 = uw[(size_t)(k + 1) * 128 + col];
            const float w2v = uw[(size_t)(k + 2) * 128 + col];
            const float w3 = uw[(size_t)(k + 3) * 128 + col];
#pragma unroll
            for (int i = 0; i < 8; i++) {
                const float4 v = *(const float4*)&xs[(half * 8 + i) * KX + k];
                acc[i] += v.x * w0;
                acc[i] += v.y * w1;
                acc[i] += v.z * w2v;
                acc[i] += v.w * w3;
            }
        }
        for (int k = 0; k < 128; k += 4) {
            const float w0 = uw[(size_t)(KX + k + 0) * 128 + col];
            const float w1 = uw[(size_t)(KX + k + 1) * 128 + col];
            const float w2v = uw[(size_t)(KX + k + 2) * 128 + col];
            const float w3 = uw[(size_t)(KX + k + 3) * 128 + col];
#pragma unroll
            for (int i = 0; i < 8; i++) {
                const float4 v = *(const float4*)&ag[(half * 8 + i) * 128 + k];
                acc[i] += v.x * w0;
                acc[i] += v.y * w1;
                acc[i] += v.z * w2v;
                acc[i] += v.w * w3;
            }
        }
#pragma unroll
        for (int i = 0; i < 8; i++) {
            const float hv = fmaxf(acc[i], 0.f);
            ah[(half * 8 + i) * 128 + col] = hv;
            if (WRITE_H)
                Hout[(size_t)(m0 + half * 8 + i) * 128 + col] = hv;
        }
    }
    __syncthreads();

    // Epilogue: Pout = h' @ [Wnext_r | Wnext_s]  (thread = 1 of 256 cols)
    {
        const int pcol = tid;
        const int side = pcol >> 7;
        const int jj   = pcol & 127;
        const float* Wp = Wnext + (size_t)(side * 128) * 128 + jj;
        float pacc[16];
#pragma unroll
        for (int i = 0; i < 16; i++) pacc[i] = 0.f;
        for (int k = 0; k < 128; k += 4) {
            const float w0 = Wp[(size_t)(k + 0) * 128];
            const float w1 = Wp[(size_t)(k + 1) * 128];
            const float w2v = Wp[(size_t)(k + 2) * 128];
            const float w3 = Wp[(size_t)(k + 3) * 128];
#pragma unroll
            for (int i = 0; i < 16; i++) {
                const float4 v = *(const float4*)&ah[i * 128 + k];
                pacc[i] += v.x * w0;
                pacc[i] += v.y * w1;
                pacc[i] += v.z * w2v;
                pacc[i] += v.w * w3;
            }
        }
#pragma unroll
        for (int i = 0; i < 16; i++)
            Pout[(size_t)(m0 + i) * 256 + pcol] = pacc[i];
    }
}

// ---------------------------------------------------------------------------
// Action head + fused finalize (validated r15).
// ---------------------------------------------------------------------------
__global__ __launch_bounds__(256) void action_head_final(const float* __restrict__ Pa,
                                                         const int* __restrict__ ei,
                                                         const float* __restrict__ edge_attr,
                                                         const int* __restrict__ mask,
                                                         const float* __restrict__ aWe,  // 16x128
                                                         const float* __restrict__ b1,
                                                         const float* __restrict__ w2,   // 128x2
                                                         const float* __restrict__ b2,   // 2
                                                         float* __restrict__ out) {
    __shared__ int   ridx[16];
    __shared__ int   sidx[16];
    __shared__ int   eidx[16];
    __shared__ float eas[16 * 16];
    __shared__ float hid[16 * 129];
    __shared__ float o01[32];

    const int b   = blockIdx.y;
    const int j0  = blockIdx.x * 16;
    const int tid = threadIdx.x;

    if (tid < 16) {
        const int e = mask[j0 + tid];
        eidx[tid]   = e;
        ridx[tid]   = ei[e];
        sidx[tid]   = ei[En + e];
    }
    __syncthreads();
    if (tid < 64) {
        const float* eab = edge_attr + (size_t)b * En * 16;
        const int e = tid >> 2, k0 = (tid & 3) * 4;
        *(float4*)&eas[e * 16 + k0] = *(const float4*)&eab[(size_t)eidx[e] * 16 + k0];
    }
    __syncthreads();

    const int col  = tid & 127;
    const int half = tid >> 7;
    float w[16];
#pragma unroll
    for (int k = 0; k < 16; k++) w[k] = aWe[k * 128 + col];
    const float b1c = b1[col];
    const float* Pab = Pa + (size_t)b * Nn * 256;

#pragma unroll
    for (int i = 0; i < 8; i++) {
        const int e = half * 8 + i;
        float a0 = b1c + Pab[(size_t)ridx[e] * 256 + col];
        float a1 = Pab[(size_t)sidx[e] * 256 + 128 + col];
        const float4 e0v = *(const float4*)&eas[e * 16 + 0];
        const float4 e1v = *(const float4*)&eas[e * 16 + 4];
        const float4 e2v = *(const float4*)&eas[e * 16 + 8];
        const float4 e3v = *(const float4*)&eas[e * 16 + 12];
        a0 += e0v.x * w[0];  a1 += e0v.y * w[1];  a0 += e0v.z * w[2];  a1 += e0v.w * w[3];
        a0 += e1v.x * w[4];  a1 += e1v.y * w[5];  a0 += e1v.z * w[6];  a1 += e1v.w * w[7];
        a0 += e2v.x * w[8];  a1 += e2v.y * w[9];  a0 += e2v.z * w[10]; a1 += e2v.w * w[11];
        a0 += e3v.x * w[12]; a1 += e3v.y * w[13]; a0 += e3v.z * w[14]; a1 += e3v.w * w[15];
        hid[e * 129 + col] = fmaxf(a0 + a1, 0.f);
    }
    __syncthreads();

    const int g    = tid >> 4;
    const int lane = tid & 15;
    float o0 = 0.f, o1 = 0.f;
#pragma unroll
    for (int k = lane; k < 128; k += 16) {
        const float hv = hid[g * 129 + k];
        o0 += hv * w2[k * 2 + 0];
        o1 += hv * w2[k * 2 + 1];
    }
#pragma unroll
    for (int m = 8; m >= 1; m >>= 1) {
        o0 += __shfl_xor(o0, m);
        o1 += __shfl_xor(o1, m);
    }
    if (lane == 0) {
        o01[g * 2 + 0] = o0 + b2[0];
        o01[g * 2 + 1] = o1 + b2[1];
    }
    __syncthreads();

    if (tid < 8) {
        const float mean = 0.5f * (o01[4 * tid + 0] + o01[4 * tid + 2]);
        float l          = 0.5f * (o01[4 * tid + 1] + o01[4 * tid + 3]);
        l = fminf(fmaxf(l, -20.f), 2.f);
        constexpr int HALF = EAn / 2;          // 40000
        const int idx = b * HALF + j0 / 2 + tid;
        out[idx]             = mean;
        out[Bn * HALF + idx] = expf(l);
    }
}

// ---------------------------------------------------------------------------
extern "C" void kernel_launch(void* const* d_in, const int* in_sizes, int n_in,
                              void* d_out, int out_size, void* d_ws, size_t ws_size,
                              hipStream_t stream) {
    (void)out_size;  // unreliable (r6); geometry is compile-time.

    static const long long want[20] = {
        (long long)Bn * Nn * 64, 2LL * En, (long long)Bn * En * 16, (long long)EAn,
        144 * 128, 128, 128 * 128, 128, 192 * 128, 128,
        272 * 128, 128, 128 * 128, 128, 256 * 128, 128,
        272 * 128, 128, 128 * 2, 2};
    bool sig_ok = (n_in == 20);
    if (sig_ok)
        for (int i = 0; i < 20; i++) sig_ok = sig_ok && (in_sizes[i] == want[i]);

    const size_t PF   = (size_t)Bn * Nn * 256;   // 10,240,000
    const size_t aggF = (size_t)Bn * Nn * 128;   //  5,120,000
    const size_t hF   = (size_t)Bn * Nn * 128;   //  5,120,000
    const size_t needWords = PF + aggF + hF + 2 * En + EAn + (Nn + 16) + En + En;
    const size_t needBytes = needWords * 4;      // ~87.4 MB

    const dim3 blk(256);
    if (!sig_ok) {
        fill_sentinel<<<(OUT_N + 255) / 256, blk, 0, stream>>>((float*)d_out, 5555.f);
        return;
    }
    if (ws_size < needBytes) {
        fill_sentinel<<<(OUT_N + 255) / 256, blk, 0, stream>>>((float*)d_out, 9999.f);
        return;
    }

    const float* nodes  = (const float*)d_in[0];
    const void*  ei_raw = d_in[1];
    const float* eattr  = (const float*)d_in[2];
    const void*  mk_raw = d_in[3];
    const float* g1_mw1 = (const float*)d_in[4];
    const float* g1_mb1 = (const float*)d_in[5];
    const float* g1_mw2 = (const float*)d_in[6];
    const float* g1_mb2 = (const float*)d_in[7];
    const float* g1_uw  = (const float*)d_in[8];
    const float* g1_ub  = (const float*)d_in[9];
    const float* g2_mw1 = (const float*)d_in[10];
    const float* g2_mb1 = (const float*)d_in[11];
    const float* g2_mw2 = (const float*)d_in[12];
    const float* g2_mb2 = (const float*)d_in[13];
    const float* g2_uw  = (const float*)d_in[14];
    const float* g2_ub  = (const float*)d_in[15];
    const float* a_w1   = (const float*)d_in[16];
    const float* a_b1   = (const float*)d_in[17];
    const float* a_w2   = (const float*)d_in[18];
    const float* a_b2   = (const float*)d_in[19];

    float*        P     = (float*)d_ws;
    float*        aggH  = P + PF;
    float*        h     = aggH + aggF;
    int*          ei32  = (int*)(h + hF);
    int*          mk32  = ei32 + 2 * En;
    int*          rowst = mk32 + EAn;
    unsigned int* rsS   = (unsigned int*)(rowst + (Nn + 16));
    int*          eidS  = (int*)(rsS + En);
    int*   degi = (int*)h;                       // CSR temporaries in dead h
    int*   cur  = degi + Nn;

    const int  nbNodes = (Bn * Nn) / 16;         // 2500
    const dim3 gEdge(En / 32, 1);                // 10000 (batch-merged)
    const dim3 gAct(EAn / 16, Bn);               // 5000 x 4
    const size_t aggBytes = aggF * 4;

    // ---- Index decode + CSR build (batch-invariant) ----
    decode_indices<<<2500, blk, 0, stream>>>(ei_raw, mk_raw, ei32, mk32, degi, cur);
    count_deg<<<En / 256, blk, 0, stream>>>(ei32, degi);
    scan_rowstart<<<1, blk, 0, stream>>>(degi, rowst);
    fill_csr<<<En / 256, blk, 0, stream>>>(ei32, rowst, cur, rsS, eidS);

    // ---- Layer 1 ----
    precompute_P<64><<<nbNodes, blk, 0, stream>>>(nodes, g1_mw1, P);
    hipMemsetAsync(aggH, 0, aggBytes, stream);
    edge_scatter_sorted<<<gEdge, blk, 0, stream>>>(P, rsS, eidS, eattr,
                                                   g1_mw1 + 128 * 128, g1_mb1, aggH);
    // h1 + P2 fused; zeroes aggH for layer 2
    fused_node_p<64, true, true><<<nbNodes, blk, 0, stream>>>(
        nodes, aggH, g1_mw2, g1_mb2, rowst, g1_uw, g1_ub, g2_mw1, h, P);

    // ---- Layer 2 ----
    edge_scatter_sorted<<<gEdge, blk, 0, stream>>>(P, rsS, eidS, eattr,
                                                   g2_mw1 + 256 * 128, g2_mb1, aggH);
    // Pa fused; h2 never materialized
    fused_node_p<128, false, false><<<nbNodes, blk, 0, stream>>>(
        h, aggH, g2_mw2, g2_mb2, rowst, g2_uw, g2_ub, a_w1, nullptr, P);

    // ---- Action head (+ fused finalize) ----
    action_head_final<<<gAct, blk, 0, stream>>>(P, ei32, eattr, mk32,
                                                a_w1 + 256 * 128, a_b1,
                                                a_w2, a_b2, (float*)d_out);
}

// Round 17
// 784.874 us; speedup vs baseline: 1.0027x; 1.0027x over previous
//
#include <hip/hip_runtime.h>
#include <hip/hip_bf16.h>
#include <math.h>

// Problem constants
constexpr int Bn  = 4;
constexpr int Nn  = 10000;
constexpr int En  = 320000;
constexpr int EAn = 80000;
constexpr int OUT_N = 2 * Bn * (EAn / 2);   // 320000 f32: mean | std

// ---------------------------------------------------------------------------
__global__ __launch_bounds__(256) void fill_sentinel(float* out, float v) {
    const int i = blockIdx.x * 256 + threadIdx.x;
    if (i < OUT_N) out[i] = v;
}

// ---------------------------------------------------------------------------
// Index decode (validated r8) + zero degi/cur.
// ---------------------------------------------------------------------------
__global__ __launch_bounds__(256) void decode_indices(const void* __restrict__ ei_raw,
                                                      const void* __restrict__ mask_raw,
                                                      int* __restrict__ ei32,
                                                      int* __restrict__ mask32,
                                                      int* __restrict__ degi,
                                                      int* __restrict__ cur) {
    __shared__ int is64;
    if (threadIdx.x == 0) {
        const long long* p = (const long long*)ei_raw;
        int ok = 1;
        for (int i = 0; i < 64; i++) {
            const long long v = p[i];
            if (v < 0 || v >= (long long)Nn) { ok = 0; break; }
        }
        is64 = ok;
    }
    __syncthreads();
    const int idx    = blockIdx.x * 256 + threadIdx.x;
    const int stride = gridDim.x * 256;
    if (is64) {
        for (int i = idx; i < 2 * En; i += stride)
            ei32[i] = (int)((const long long*)ei_raw)[i];
        for (int i = idx; i < EAn; i += stride)
            mask32[i] = (int)((const long long*)mask_raw)[i];
    } else {
        for (int i = idx; i < 2 * En; i += stride)
            ei32[i] = ((const int*)ei_raw)[i];
        for (int i = idx; i < EAn; i += stride)
            mask32[i] = ((const int*)mask_raw)[i];
    }
    for (int i = idx; i < Nn; i += stride) { degi[i] = 0; cur[i] = 0; }
}

// --------------------------- CSR construction (validated r10/r11) -----------
__global__ __launch_bounds__(256) void count_deg(const int* __restrict__ ei,
                                                 int* __restrict__ degi) {
    const int e = blockIdx.x * 256 + threadIdx.x;
    if (e < En) atomicAdd(&degi[ei[e]], 1);
}

// Exclusive scan, 1024 threads (10 iters instead of 40 — serial-kernel cut).
__global__ __launch_bounds__(1024) void scan_rowstart(const int* __restrict__ degi,
                                                      int* __restrict__ row_start) {
    __shared__ int wsum[16];
    __shared__ int carry_s;
    const int tid  = threadIdx.x;
    const int lane = tid & 63;
    const int wv   = tid >> 6;
    if (tid == 0) { carry_s = 0; row_start[0] = 0; }
    __syncthreads();
    for (int t = 0; t < 10; t++) {             // 10*1024 = 10240 >= Nn
        const int i = t * 1024 + tid;
        int v = (i < Nn) ? degi[i] : 0;
#pragma unroll
        for (int off = 1; off < 64; off <<= 1) {
            const int x = __shfl_up(v, off);
            if (lane >= off) v += x;
        }
        if (lane == 63) wsum[wv] = v;
        __syncthreads();
        int add = 0;
        for (int w = 0; w < wv; w++) add += wsum[w];
        const int base = carry_s;
        if (i < Nn) row_start[i + 1] = base + add + v;
        __syncthreads();
        if (tid == 1023) carry_s = base + add + v;
        __syncthreads();
    }
}

// rs_sorted[pos] = (r<<16)|s  (both < 2^16); eid_sorted[pos] = original edge id.
__global__ __launch_bounds__(256) void fill_csr(const int* __restrict__ ei,
                                                const int* __restrict__ row_start,
                                                int* __restrict__ cursor,
                                                unsigned int* __restrict__ rs_sorted,
                                                int* __restrict__ eid_sorted) {
    const int e = blockIdx.x * 256 + threadIdx.x;
    if (e < En) {
        const int r   = ei[e];
        const int s   = ei[En + e];
        const int pos = row_start[r] + atomicAdd(&cursor[r], 1);
        rs_sorted[pos]  = ((unsigned int)r << 16) | (unsigned int)s;
        eid_sorted[pos] = e;
    }
}

// ---------------------------------------------------------------------------
// P = X @ [Wr | Ws] -> (B*N, 256). (r13 version — layer 1 only)
// ---------------------------------------------------------------------------
template <int KX>
__global__ __launch_bounds__(256) void precompute_P(const float* __restrict__ X,
                                                    const float* __restrict__ W,
                                                    float* __restrict__ P) {
    __shared__ float xs[16 * KX];
    const int m0  = blockIdx.x * 16;
    const int tid = threadIdx.x;

    for (int idx = tid * 4; idx < 16 * KX; idx += 1024)
        *(float4*)&xs[idx] = *(const float4*)&X[(size_t)m0 * KX + idx];
    __syncthreads();

    const int col  = tid;
    const int side = col >> 7;
    const int jj   = col & 127;
    const float* Wp = W + (size_t)(side * KX) * 128 + jj;

    float acc[16];
#pragma unroll
    for (int i = 0; i < 16; i++) acc[i] = 0.f;

    for (int k = 0; k < KX; k += 4) {
        const float w0 = Wp[(size_t)(k + 0) * 128];
        const float w1 = Wp[(size_t)(k + 1) * 128];
        const float w2 = Wp[(size_t)(k + 2) * 128];
        const float w3 = Wp[(size_t)(k + 3) * 128];
#pragma unroll
        for (int i = 0; i < 16; i++) {
            const float4 x = *(const float4*)&xs[i * KX + k];
            acc[i] += x.x * w0;
            acc[i] += x.y * w1;
            acc[i] += x.z * w2;
            acc[i] += x.w * w3;
        }
    }
#pragma unroll
    for (int i = 0; i < 16; i++) P[(size_t)(m0 + i) * 256 + col] = acc[i];
}

// ---------------------------------------------------------------------------
// Edge scatter — r14 body (best-ever: 181 µs, VGPR 28, occ 86%, single
// accumulator chain, per-batch grid) + run-hoisted P_r: the receiver row is
// gathered only at run boundaries (wave-uniform branch; sorted edges give
// ~1.5 distinct receivers per 16-edge window -> ~15/16 of P_r gathers were
// redundant). Batch-merge REVERTED (r16: working set 4x -> latency-bound).
// ---------------------------------------------------------------------------
__global__ __launch_bounds__(256) void edge_scatter_sorted(const float* __restrict__ P,
                                                           const unsigned int* __restrict__ rs_sorted,
                                                           const int* __restrict__ eid_sorted,
                                                           const float* __restrict__ edge_attr,
                                                           const float* __restrict__ We,  // 16x128
                                                           const float* __restrict__ b1,
                                                           float* __restrict__ aggH) {
    __shared__ int   rc[32], sc[32], ec[32];
    __shared__ float eas[32 * 16];

    const int b   = blockIdx.y;
    const int e0  = blockIdx.x * 32;
    const int tid = threadIdx.x;

    if (tid < 32) {
        const unsigned int v = rs_sorted[e0 + tid];
        rc[tid] = (int)(v >> 16);
        sc[tid] = (int)(v & 0xffffu);
        ec[tid] = eid_sorted[e0 + tid];
    }
    __syncthreads();
    {
        const float* eab = edge_attr + (size_t)b * En * 16;
        if (tid < 128) {
            const int e = tid >> 2, k0 = (tid & 3) * 4;
            *(float4*)&eas[e * 16 + k0] = *(const float4*)&eab[(size_t)ec[e] * 16 + k0];
        }
    }
    __syncthreads();

    const int col  = tid & 127;
    const int half = tid >> 7;
    const int eb   = half * 16;

    float w[16];
#pragma unroll
    for (int k = 0; k < 16; k++) w[k] = We[k * 128 + col];
    const float b1c = b1[col];

    const float* Pb   = P + (size_t)b * Nn * 256;
    float*       aggb = aggH + (size_t)b * Nn * 128;

    int   curR = rc[eb];
    float prv  = b1c + Pb[(size_t)curR * 256 + col];
    float run  = 0.f;
#pragma unroll 4
    for (int i = 0; i < 16; i++) {
        const int e = eb + i;
        const int r = rc[e];
        if (r != curR) {                       // wave-uniform branch
            atomicAdd(&aggb[(size_t)curR * 128 + col], run);
            run  = 0.f;
            curR = r;
            prv  = b1c + Pb[(size_t)r * 256 + col];
        }
        float a = prv + Pb[(size_t)sc[e] * 256 + 128 + col];
        const float4 e0v = *(const float4*)&eas[e * 16 + 0];
        const float4 e1v = *(const float4*)&eas[e * 16 + 4];
        const float4 e2v = *(const float4*)&eas[e * 16 + 8];
        const float4 e3v = *(const float4*)&eas[e * 16 + 12];
        a += e0v.x * w[0];  a += e0v.y * w[1];  a += e0v.z * w[2];  a += e0v.w * w[3];
        a += e1v.x * w[4];  a += e1v.y * w[5];  a += e1v.z * w[6];  a += e1v.w * w[7];
        a += e2v.x * w[8];  a += e2v.y * w[9];  a += e2v.z * w[10]; a += e2v.w * w[11];
        a += e3v.x * w[12]; a += e3v.y * w[13]; a += e3v.z * w[14]; a += e3v.w * w[15];
        run += fmaxf(a, 0.f);
    }
    atomicAdd(&aggb[(size_t)curR * 128 + col], run);
}

// ---------------------------------------------------------------------------
// Fused node + next-stage P epilogue (validated r15).
// ---------------------------------------------------------------------------
template <int KX, bool ZERO_AGG, bool WRITE_H>
__global__ __launch_bounds__(256) void fused_node_p(const float* __restrict__ X,
                                                    float* __restrict__ aggH,
                                                    const float* __restrict__ W2,
                                                    const float* __restrict__ b2,
                                                    const int* __restrict__ row_start,
                                                    const float* __restrict__ uw,
                                                    const float* __restrict__ ub,
                                                    const float* __restrict__ Wnext, // >=256 x 128
                                                    float* __restrict__ Hout,
                                                    float* __restrict__ Pout) {
    __shared__ float ah[16 * 128];
    __shared__ float ag[16 * 128];
    __shared__ float xs[16 * KX];
    __shared__ float dg[16];

    const int m0  = blockIdx.x * 16;     // Nn % 16 == 0 -> never straddles batch
    const int tid = threadIdx.x;

    if (tid < 16) {
        const int row = m0 + tid;
        const int nl  = row - (row / Nn) * Nn;
        dg[tid] = (float)(row_start[nl + 1] - row_start[nl]);
    }
    for (int idx = tid * 4; idx < 16 * 128; idx += 1024)
        *(float4*)&ah[idx] = *(const float4*)&aggH[(size_t)m0 * 128 + idx];
    for (int idx = tid * 4; idx < 16 * KX; idx += 1024)
        *(float4*)&xs[idx] = *(const float4*)&X[(size_t)m0 * KX + idx];
    __syncthreads();

    if (ZERO_AGG) {  // own rows only; consumed into LDS above
        const float4 z = {0.f, 0.f, 0.f, 0.f};
        for (int idx = tid * 4; idx < 16 * 128; idx += 1024)
            *(float4*)&aggH[(size_t)m0 * 128 + idx] = z;
    }

    const int col  = tid & 127;
    const int half = tid >> 7;

    {   // Phase A: ag = ah @ W2 + dg*b2
        const float b2c = b2[col];
        float acc[8];
#pragma unroll
        for (int i = 0; i < 8; i++) acc[i] = dg[half * 8 + i] * b2c;
        for (int k = 0; k < 128; k += 4) {
            const float w0 = W2[(k + 0) * 128 + col];
            const float w1 = W2[(k + 1) * 128 + col];
            const float w2v = W2[(k + 2) * 128 + col];
            const float w3 = W2[(k + 3) * 128 + col];
#pragma unroll
            for (int i = 0; i < 8; i++) {
                const float4 v = *(const float4*)&ah[(half * 8 + i) * 128 + k];
                acc[i] += v.x * w0;
                acc[i] += v.y * w1;
                acc[i] += v.z * w2v;
                acc[i] += v.w * w3;
            }
        }
#pragma unroll
        for (int i = 0; i < 8; i++) ag[(half * 8 + i) * 128 + col] = acc[i];
    }
    __syncthreads();

    // Phase B: h' = relu([X | ag] @ uw + ub) -> ah (reuse) [+ global]
    {
        float acc[8];
#pragma unroll
        for (int i = 0; i < 8; i++) acc[i] = ub[col];
        for (int k = 0; k < KX; k += 4) {
            const float w0 = uw[(size_t)(k + 0) * 128 + col];
            const float w1 = uw[(size_t)(k + 1) * 128 + col];
            const float w2v = uw[(size_t)(k + 2) * 128 + col];
            const float w3 = uw[(size_t)(k + 3) * 128 + col];
#pragma unroll
            for (int i = 0; i < 8; i++) {
                const float4 v = *(const float4*)&xs[(half * 8 + i) * KX + k];
                acc[i] += v.x * w0;
                acc[i] += v.y * w1;
                acc[i] += v.z * w2v;
                acc[i] += v.w * w3;
            }
        }
        for (int k = 0; k < 128; k += 4) {
            const float w0 = uw[(size_t)(KX + k + 0) * 128 + col];
            const float w1 = uw[(size_t)(KX + k + 1) * 128 + col];
            const float w2v = uw[(size_t)(KX + k + 2) * 128 + col];
            const float w3 = uw[(size_t)(KX + k + 3) * 128 + col];
#pragma unroll
            for (int i = 0; i < 8; i++) {
                const float4 v = *(const float4*)&ag[(half * 8 + i) * 128 + k];
                acc[i] += v.x * w0;
                acc[i] += v.y * w1;
                acc[i] += v.z * w2v;
                acc[i] += v.w * w3;
            }
        }
#pragma unroll
        for (int i = 0; i < 8; i++) {
            const float hv = fmaxf(acc[i], 0.f);
            ah[(half * 8 + i) * 128 + col] = hv;
            if (WRITE_H)
                Hout[(size_t)(m0 + half * 8 + i) * 128 + col] = hv;
        }
    }
    __syncthreads();

    // Epilogue: Pout = h' @ [Wnext_r | Wnext_s]  (thread = 1 of 256 cols)
    {
        const int pcol = tid;
        const int side = pcol >> 7;
        const int jj   = pcol & 127;
        const float* Wp = Wnext + (size_t)(side * 128) * 128 + jj;
        float pacc[16];
#pragma unroll
        for (int i = 0; i < 16; i++) pacc[i] = 0.f;
        for (int k = 0; k < 128; k += 4) {
            const float w0 = Wp[(size_t)(k + 0) * 128];
            const float w1 = Wp[(size_t)(k + 1) * 128];
            const float w2v = Wp[(size_t)(k + 2) * 128];
            const float w3 = Wp[(size_t)(k + 3) * 128];
#pragma unroll
            for (int i = 0; i < 16; i++) {
                const float4 v = *(const float4*)&ah[i * 128 + k];
                pacc[i] += v.x * w0;
                pacc[i] += v.y * w1;
                pacc[i] += v.z * w2v;
                pacc[i] += v.w * w3;
            }
        }
#pragma unroll
        for (int i = 0; i < 16; i++)
            Pout[(size_t)(m0 + i) * 256 + pcol] = pacc[i];
    }
}

// ---------------------------------------------------------------------------
// Action head + fused finalize (validated r15).
// ---------------------------------------------------------------------------
__global__ __launch_bounds__(256) void action_head_final(const float* __restrict__ Pa,
                                                         const int* __restrict__ ei,
                                                         const float* __restrict__ edge_attr,
                                                         const int* __restrict__ mask,
                                                         const float* __restrict__ aWe,  // 16x128
                                                         const float* __restrict__ b1,
                                                         const float* __restrict__ w2,   // 128x2
                                                         const float* __restrict__ b2,   // 2
                                                         float* __restrict__ out) {
    __shared__ int   ridx[16];
    __shared__ int   sidx[16];
    __shared__ int   eidx[16];
    __shared__ float eas[16 * 16];
    __shared__ float hid[16 * 129];
    __shared__ float o01[32];

    const int b   = blockIdx.y;
    const int j0  = blockIdx.x * 16;
    const int tid = threadIdx.x;

    if (tid < 16) {
        const int e = mask[j0 + tid];
        eidx[tid]   = e;
        ridx[tid]   = ei[e];
        sidx[tid]   = ei[En + e];
    }
    __syncthreads();
    if (tid < 64) {
        const float* eab = edge_attr + (size_t)b * En * 16;
        const int e = tid >> 2, k0 = (tid & 3) * 4;
        *(float4*)&eas[e * 16 + k0] = *(const float4*)&eab[(size_t)eidx[e] * 16 + k0];
    }
    __syncthreads();

    const int col  = tid & 127;
    const int half = tid >> 7;
    float w[16];
#pragma unroll
    for (int k = 0; k < 16; k++) w[k] = aWe[k * 128 + col];
    const float b1c = b1[col];
    const float* Pab = Pa + (size_t)b * Nn * 256;

#pragma unroll
    for (int i = 0; i < 8; i++) {
        const int e = half * 8 + i;
        float a = b1c + Pab[(size_t)ridx[e] * 256 + col]
                      + Pab[(size_t)sidx[e] * 256 + 128 + col];
        const float4 e0v = *(const float4*)&eas[e * 16 + 0];
        const float4 e1v = *(const float4*)&eas[e * 16 + 4];
        const float4 e2v = *(const float4*)&eas[e * 16 + 8];
        const float4 e3v = *(const float4*)&eas[e * 16 + 12];
        a += e0v.x * w[0];  a += e0v.y * w[1];  a += e0v.z * w[2];  a += e0v.w * w[3];
        a += e1v.x * w[4];  a += e1v.y * w[5];  a += e1v.z * w[6];  a += e1v.w * w[7];
        a += e2v.x * w[8];  a += e2v.y * w[9];  a += e2v.z * w[10]; a += e2v.w * w[11];
        a += e3v.x * w[12]; a += e3v.y * w[13]; a += e3v.z * w[14]; a += e3v.w * w[15];
        hid[e * 129 + col] = fmaxf(a, 0.f);
    }
    __syncthreads();

    const int g    = tid >> 4;
    const int lane = tid & 15;
    float o0 = 0.f, o1 = 0.f;
#pragma unroll
    for (int k = lane; k < 128; k += 16) {
        const float hv = hid[g * 129 + k];
        o0 += hv * w2[k * 2 + 0];
        o1 += hv * w2[k * 2 + 1];
    }
#pragma unroll
    for (int m = 8; m >= 1; m >>= 1) {
        o0 += __shfl_xor(o0, m);
        o1 += __shfl_xor(o1, m);
    }
    if (lane == 0) {
        o01[g * 2 + 0] = o0 + b2[0];
        o01[g * 2 + 1] = o1 + b2[1];
    }
    __syncthreads();

    if (tid < 8) {
        const float mean = 0.5f * (o01[4 * tid + 0] + o01[4 * tid + 2]);
        float l          = 0.5f * (o01[4 * tid + 1] + o01[4 * tid + 3]);
        l = fminf(fmaxf(l, -20.f), 2.f);
        constexpr int HALF = EAn / 2;          // 40000
        const int idx = b * HALF + j0 / 2 + tid;
        out[idx]             = mean;
        out[Bn * HALF + idx] = expf(l);
    }
}

// ---------------------------------------------------------------------------
extern "C" void kernel_launch(void* const* d_in, const int* in_sizes, int n_in,
                              void* d_out, int out_size, void* d_ws, size_t ws_size,
                              hipStream_t stream) {
    (void)out_size;  // unreliable (r6); geometry is compile-time.

    static const long long want[20] = {
        (long long)Bn * Nn * 64, 2LL * En, (long long)Bn * En * 16, (long long)EAn,
        144 * 128, 128, 128 * 128, 128, 192 * 128, 128,
        272 * 128, 128, 128 * 128, 128, 256 * 128, 128,
        272 * 128, 128, 128 * 2, 2};
    bool sig_ok = (n_in == 20);
    if (sig_ok)
        for (int i = 0; i < 20; i++) sig_ok = sig_ok && (in_sizes[i] == want[i]);

    const size_t PF   = (size_t)Bn * Nn * 256;   // 10,240,000
    const size_t aggF = (size_t)Bn * Nn * 128;   //  5,120,000
    const size_t hF   = (size_t)Bn * Nn * 128;   //  5,120,000
    const size_t needWords = PF + aggF + hF + 2 * En + EAn + (Nn + 16) + En + En;
    const size_t needBytes = needWords * 4;      // ~87.4 MB

    const dim3 blk(256);
    if (!sig_ok) {
        fill_sentinel<<<(OUT_N + 255) / 256, blk, 0, stream>>>((float*)d_out, 5555.f);
        return;
    }
    if (ws_size < needBytes) {
        fill_sentinel<<<(OUT_N + 255) / 256, blk, 0, stream>>>((float*)d_out, 9999.f);
        return;
    }

    const float* nodes  = (const float*)d_in[0];
    const void*  ei_raw = d_in[1];
    const float* eattr  = (const float*)d_in[2];
    const void*  mk_raw = d_in[3];
    const float* g1_mw1 = (const float*)d_in[4];
    const float* g1_mb1 = (const float*)d_in[5];
    const float* g1_mw2 = (const float*)d_in[6];
    const float* g1_mb2 = (const float*)d_in[7];
    const float* g1_uw  = (const float*)d_in[8];
    const float* g1_ub  = (const float*)d_in[9];
    const float* g2_mw1 = (const float*)d_in[10];
    const float* g2_mb1 = (const float*)d_in[11];
    const float* g2_mw2 = (const float*)d_in[12];
    const float* g2_mb2 = (const float*)d_in[13];
    const float* g2_uw  = (const float*)d_in[14];
    const float* g2_ub  = (const float*)d_in[15];
    const float* a_w1   = (const float*)d_in[16];
    const float* a_b1   = (const float*)d_in[17];
    const float* a_w2   = (const float*)d_in[18];
    const float* a_b2   = (const float*)d_in[19];

    float*        P     = (float*)d_ws;
    float*        aggH  = P + PF;
    float*        h     = aggH + aggF;
    int*          ei32  = (int*)(h + hF);
    int*          mk32  = ei32 + 2 * En;
    int*          rowst = mk32 + EAn;
    unsigned int* rsS   = (unsigned int*)(rowst + (Nn + 16));
    int*          eidS  = (int*)(rsS + En);
    int*   degi = (int*)h;                       // CSR temporaries in dead h
    int*   cur  = degi + Nn;

    const int  nbNodes = (Bn * Nn) / 16;         // 2500
    const dim3 gEdge(En / 32, Bn);               // 10000 x 4 (per-batch, r14 proven)
    const dim3 gAct(EAn / 16, Bn);               // 5000 x 4
    const size_t aggBytes = aggF * 4;

    // ---- Index decode + CSR build (batch-invariant) ----
    decode_indices<<<2500, blk, 0, stream>>>(ei_raw, mk_raw, ei32, mk32, degi, cur);
    count_deg<<<En / 256, blk, 0, stream>>>(ei32, degi);
    scan_rowstart<<<1, dim3(1024), 0, stream>>>(degi, rowst);
    fill_csr<<<En / 256, blk, 0, stream>>>(ei32, rowst, cur, rsS, eidS);

    // ---- Layer 1 ----
    precompute_P<64><<<nbNodes, blk, 0, stream>>>(nodes, g1_mw1, P);
    hipMemsetAsync(aggH, 0, aggBytes, stream);
    edge_scatter_sorted<<<gEdge, blk, 0, stream>>>(P, rsS, eidS, eattr,
                                                   g1_mw1 + 128 * 128, g1_mb1, aggH);
    // h1 + P2 fused; zeroes aggH for layer 2
    fused_node_p<64, true, true><<<nbNodes, blk, 0, stream>>>(
        nodes, aggH, g1_mw2, g1_mb2, rowst, g1_uw, g1_ub, g2_mw1, h, P);

    // ---- Layer 2 ----
    edge_scatter_sorted<<<gEdge, blk, 0, stream>>>(P, rsS, eidS, eattr,
                                                   g2_mw1 + 256 * 128, g2_mb1, aggH);
    // Pa fused; h2 never materialized
    fused_node_p<128, false, false><<<nbNodes, blk, 0, stream>>>(
        h, aggH, g2_mw2, g2_mb2, rowst, g2_uw, g2_ub, a_w1, nullptr, P);

    // ---- Action head (+ fused finalize) ----
    action_head_final<<<gAct, blk, 0, stream>>>(P, ei32, eattr, mk32,
                                                a_w1 + 256 * 128, a_b1,
                                                a_w2, a_b2, (float*)d_out);
}

// Round 18
// 722.996 us; speedup vs baseline: 1.0885x; 1.0856x over previous
//
#include <hip/hip_runtime.h>
#include <hip/hip_bf16.h>
#include <math.h>

// Problem constants
constexpr int Bn  = 4;
constexpr int Nn  = 10000;
constexpr int En  = 320000;
constexpr int EAn = 80000;
constexpr int OUT_N = 2 * Bn * (EAn / 2);   // 320000 f32: mean | std

// ---------------------------------------------------------------------------
__global__ __launch_bounds__(256) void fill_sentinel(float* out, float v) {
    const int i = blockIdx.x * 256 + threadIdx.x;
    if (i < OUT_N) out[i] = v;
}

// ---------------------------------------------------------------------------
// Index decode (validated r8) + zero degi/cur.
// ---------------------------------------------------------------------------
__global__ __launch_bounds__(256) void decode_indices(const void* __restrict__ ei_raw,
                                                      const void* __restrict__ mask_raw,
                                                      int* __restrict__ ei32,
                                                      int* __restrict__ mask32,
                                                      int* __restrict__ degi,
                                                      int* __restrict__ cur) {
    __shared__ int is64;
    if (threadIdx.x == 0) {
        const long long* p = (const long long*)ei_raw;
        int ok = 1;
        for (int i = 0; i < 64; i++) {
            const long long v = p[i];
            if (v < 0 || v >= (long long)Nn) { ok = 0; break; }
        }
        is64 = ok;
    }
    __syncthreads();
    const int idx    = blockIdx.x * 256 + threadIdx.x;
    const int stride = gridDim.x * 256;
    if (is64) {
        for (int i = idx; i < 2 * En; i += stride)
            ei32[i] = (int)((const long long*)ei_raw)[i];
        for (int i = idx; i < EAn; i += stride)
            mask32[i] = (int)((const long long*)mask_raw)[i];
    } else {
        for (int i = idx; i < 2 * En; i += stride)
            ei32[i] = ((const int*)ei_raw)[i];
        for (int i = idx; i < EAn; i += stride)
            mask32[i] = ((const int*)mask_raw)[i];
    }
    for (int i = idx; i < Nn; i += stride) { degi[i] = 0; cur[i] = 0; }
}

// --------------------------- CSR construction (validated r10/r11) -----------
__global__ __launch_bounds__(256) void count_deg(const int* __restrict__ ei,
                                                 int* __restrict__ degi) {
    const int e = blockIdx.x * 256 + threadIdx.x;
    if (e < En) atomicAdd(&degi[ei[e]], 1);
}

// Exclusive scan, 1024 threads (validated r17).
__global__ __launch_bounds__(1024) void scan_rowstart(const int* __restrict__ degi,
                                                      int* __restrict__ row_start) {
    __shared__ int wsum[16];
    __shared__ int carry_s;
    const int tid  = threadIdx.x;
    const int lane = tid & 63;
    const int wv   = tid >> 6;
    if (tid == 0) { carry_s = 0; row_start[0] = 0; }
    __syncthreads();
    for (int t = 0; t < 10; t++) {             // 10*1024 = 10240 >= Nn
        const int i = t * 1024 + tid;
        int v = (i < Nn) ? degi[i] : 0;
#pragma unroll
        for (int off = 1; off < 64; off <<= 1) {
            const int x = __shfl_up(v, off);
            if (lane >= off) v += x;
        }
        if (lane == 63) wsum[wv] = v;
        __syncthreads();
        int add = 0;
        for (int w = 0; w < wv; w++) add += wsum[w];
        const int base = carry_s;
        if (i < Nn) row_start[i + 1] = base + add + v;
        __syncthreads();
        if (tid == 1023) carry_s = base + add + v;
        __syncthreads();
    }
}

// rs_sorted[pos] = (r<<16)|s  (both < 2^16); eid_sorted[pos] = original edge id.
__global__ __launch_bounds__(256) void fill_csr(const int* __restrict__ ei,
                                                const int* __restrict__ row_start,
                                                int* __restrict__ cursor,
                                                unsigned int* __restrict__ rs_sorted,
                                                int* __restrict__ eid_sorted) {
    const int e = blockIdx.x * 256 + threadIdx.x;
    if (e < En) {
        const int r   = ei[e];
        const int s   = ei[En + e];
        const int pos = row_start[r] + atomicAdd(&cursor[r], 1);
        rs_sorted[pos]  = ((unsigned int)r << 16) | (unsigned int)s;
        eid_sorted[pos] = e;
    }
}

// ---------------------------------------------------------------------------
// P = X @ [Wr | Ws] -> (B*N, 256). (r13 version — layer 1 only)
// ---------------------------------------------------------------------------
template <int KX>
__global__ __launch_bounds__(256) void precompute_P(const float* __restrict__ X,
                                                    const float* __restrict__ W,
                                                    float* __restrict__ P) {
    __shared__ float xs[16 * KX];
    const int m0  = blockIdx.x * 16;
    const int tid = threadIdx.x;

    for (int idx = tid * 4; idx < 16 * KX; idx += 1024)
        *(float4*)&xs[idx] = *(const float4*)&X[(size_t)m0 * KX + idx];
    __syncthreads();

    const int col  = tid;
    const int side = col >> 7;
    const int jj   = col & 127;
    const float* Wp = W + (size_t)(side * KX) * 128 + jj;

    float acc[16];
#pragma unroll
    for (int i = 0; i < 16; i++) acc[i] = 0.f;

    for (int k = 0; k < KX; k += 4) {
        const float w0 = Wp[(size_t)(k + 0) * 128];
        const float w1 = Wp[(size_t)(k + 1) * 128];
        const float w2 = Wp[(size_t)(k + 2) * 128];
        const float w3 = Wp[(size_t)(k + 3) * 128];
#pragma unroll
        for (int i = 0; i < 16; i++) {
            const float4 x = *(const float4*)&xs[i * KX + k];
            acc[i] += x.x * w0;
            acc[i] += x.y * w1;
            acc[i] += x.z * w2;
            acc[i] += x.w * w3;
        }
    }
#pragma unroll
    for (int i = 0; i < 16; i++) P[(size_t)(m0 + i) * 256 + col] = acc[i];
}

// ---------------------------------------------------------------------------
// Edge scatter — r14 body VERBATIM (proven local optimum: 181 µs/layer,
// VGPR 28, occ 86%, VALUBusy 80%). Three falsified "improvements":
//   dual-acc (r15, +11µs), batch-merge (r16, latency collapse),
//   run-hoisted P_r (r17, +31µs: branch serialized the gather issue).
// Unconditional per-edge gathers preserve memory-level parallelism.
// ---------------------------------------------------------------------------
__global__ __launch_bounds__(256) void edge_scatter_sorted(const float* __restrict__ P,
                                                           const unsigned int* __restrict__ rs_sorted,
                                                           const int* __restrict__ eid_sorted,
                                                           const float* __restrict__ edge_attr,
                                                           const float* __restrict__ We,  // 16x128
                                                           const float* __restrict__ b1,
                                                           float* __restrict__ aggH) {
    __shared__ int   rc[32], sc[32], ec[32];
    __shared__ float eas[32 * 16];

    const int b   = blockIdx.y;
    const int e0  = blockIdx.x * 32;
    const int tid = threadIdx.x;

    if (tid < 32) {
        const unsigned int v = rs_sorted[e0 + tid];
        rc[tid] = (int)(v >> 16);
        sc[tid] = (int)(v & 0xffffu);
        ec[tid] = eid_sorted[e0 + tid];
    }
    __syncthreads();
    {
        const float* eab = edge_attr + (size_t)b * En * 16;
        if (tid < 128) {
            const int e = tid >> 2, k0 = (tid & 3) * 4;
            *(float4*)&eas[e * 16 + k0] = *(const float4*)&eab[(size_t)ec[e] * 16 + k0];
        }
    }
    __syncthreads();

    const int col  = tid & 127;
    const int half = tid >> 7;
    const int eb   = half * 16;

    float w[16];
#pragma unroll
    for (int k = 0; k < 16; k++) w[k] = We[k * 128 + col];
    const float b1c = b1[col];

    const float* Pb   = P + (size_t)b * Nn * 256;
    float*       aggb = aggH + (size_t)b * Nn * 128;

    float run  = 0.f;
    int   curR = rc[eb];
#pragma unroll 4
    for (int i = 0; i < 16; i++) {
        const int e = eb + i;
        const int r = rc[e];
        float a = b1c + Pb[(size_t)r * 256 + col]
                      + Pb[(size_t)sc[e] * 256 + 128 + col];
        const float4 e0v = *(const float4*)&eas[e * 16 + 0];
        const float4 e1v = *(const float4*)&eas[e * 16 + 4];
        const float4 e2v = *(const float4*)&eas[e * 16 + 8];
        const float4 e3v = *(const float4*)&eas[e * 16 + 12];
        a += e0v.x * w[0];  a += e0v.y * w[1];  a += e0v.z * w[2];  a += e0v.w * w[3];
        a += e1v.x * w[4];  a += e1v.y * w[5];  a += e1v.z * w[6];  a += e1v.w * w[7];
        a += e2v.x * w[8];  a += e2v.y * w[9];  a += e2v.z * w[10]; a += e2v.w * w[11];
        a += e3v.x * w[12]; a += e3v.y * w[13]; a += e3v.z * w[14]; a += e3v.w * w[15];
        if (r != curR) {
            atomicAdd(&aggb[(size_t)curR * 128 + col], run);
            run  = 0.f;
            curR = r;
        }
        run += fmaxf(a, 0.f);
    }
    atomicAdd(&aggb[(size_t)curR * 128 + col], run);
}

// ---------------------------------------------------------------------------
// Fused node + next-stage P epilogue (validated r15).
// ---------------------------------------------------------------------------
template <int KX, bool ZERO_AGG, bool WRITE_H>
__global__ __launch_bounds__(256) void fused_node_p(const float* __restrict__ X,
                                                    float* __restrict__ aggH,
                                                    const float* __restrict__ W2,
                                                    const float* __restrict__ b2,
                                                    const int* __restrict__ row_start,
                                                    const float* __restrict__ uw,
                                                    const float* __restrict__ ub,
                                                    const float* __restrict__ Wnext, // >=256 x 128
                                                    float* __restrict__ Hout,
                                                    float* __restrict__ Pout) {
    __shared__ float ah[16 * 128];
    __shared__ float ag[16 * 128];
    __shared__ float xs[16 * KX];
    __shared__ float dg[16];

    const int m0  = blockIdx.x * 16;     // Nn % 16 == 0 -> never straddles batch
    const int tid = threadIdx.x;

    if (tid < 16) {
        const int row = m0 + tid;
        const int nl  = row - (row / Nn) * Nn;
        dg[tid] = (float)(row_start[nl + 1] - row_start[nl]);
    }
    for (int idx = tid * 4; idx < 16 * 128; idx += 1024)
        *(float4*)&ah[idx] = *(const float4*)&aggH[(size_t)m0 * 128 + idx];
    for (int idx = tid * 4; idx < 16 * KX; idx += 1024)
        *(float4*)&xs[idx] = *(const float4*)&X[(size_t)m0 * KX + idx];
    __syncthreads();

    if (ZERO_AGG) {  // own rows only; consumed into LDS above
        const float4 z = {0.f, 0.f, 0.f, 0.f};
        for (int idx = tid * 4; idx < 16 * 128; idx += 1024)
            *(float4*)&aggH[(size_t)m0 * 128 + idx] = z;
    }

    const int col  = tid & 127;
    const int half = tid >> 7;

    {   // Phase A: ag = ah @ W2 + dg*b2
        const float b2c = b2[col];
        float acc[8];
#pragma unroll
        for (int i = 0; i < 8; i++) acc[i] = dg[half * 8 + i] * b2c;
        for (int k = 0; k < 128; k += 4) {
            const float w0 = W2[(k + 0) * 128 + col];
            const float w1 = W2[(k + 1) * 128 + col];
            const float w2v = W2[(k + 2) * 128 + col];
            const float w3 = W2[(k + 3) * 128 + col];
#pragma unroll
            for (int i = 0; i < 8; i++) {
                const float4 v = *(const float4*)&ah[(half * 8 + i) * 128 + k];
                acc[i] += v.x * w0;
                acc[i] += v.y * w1;
                acc[i] += v.z * w2v;
                acc[i] += v.w * w3;
            }
        }
#pragma unroll
        for (int i = 0; i < 8; i++) ag[(half * 8 + i) * 128 + col] = acc[i];
    }
    __syncthreads();

    // Phase B: h' = relu([X | ag] @ uw + ub) -> ah (reuse) [+ global]
    {
        float acc[8];
#pragma unroll
        for (int i = 0; i < 8; i++) acc[i] = ub[col];
        for (int k = 0; k < KX; k += 4) {
            const float w0 = uw[(size_t)(k + 0) * 128 + col];
            const float w1 = uw[(size_t)(k + 1) * 128 + col];
            const float w2v = uw[(size_t)(k + 2) * 128 + col];
            const float w3 = uw[(size_t)(k + 3) * 128 + col];
#pragma unroll
            for (int i = 0; i < 8; i++) {
                const float4 v = *(const float4*)&xs[(half * 8 + i) * KX + k];
                acc[i] += v.x * w0;
                acc[i] += v.y * w1;
                acc[i] += v.z * w2v;
                acc[i] += v.w * w3;
            }
        }
        for (int k = 0; k < 128; k += 4) {
            const float w0 = uw[(size_t)(KX + k + 0) * 128 + col];
            const float w1 = uw[(size_t)(KX + k + 1) * 128 + col];
            const float w2v = uw[(size_t)(KX + k + 2) * 128 + col];
            const float w3 = uw[(size_t)(KX + k + 3) * 128 + col];
#pragma unroll
            for (int i = 0; i < 8; i++) {
                const float4 v = *(const float4*)&ag[(half * 8 + i) * 128 + k];
                acc[i] += v.x * w0;
                acc[i] += v.y * w1;
                acc[i] += v.z * w2v;
                acc[i] += v.w * w3;
            }
        }
#pragma unroll
        for (int i = 0; i < 8; i++) {
            const float hv = fmaxf(acc[i], 0.f);
            ah[(half * 8 + i) * 128 + col] = hv;
            if (WRITE_H)
                Hout[(size_t)(m0 + half * 8 + i) * 128 + col] = hv;
        }
    }
    __syncthreads();

    // Epilogue: Pout = h' @ [Wnext_r | Wnext_s]  (thread = 1 of 256 cols)
    {
        const int pcol = tid;
        const int side = pcol >> 7;
        const int jj   = pcol & 127;
        const float* Wp = Wnext + (size_t)(side * 128) * 128 + jj;
        float pacc[16];
#pragma unroll
        for (int i = 0; i < 16; i++) pacc[i] = 0.f;
        for (int k = 0; k < 128; k += 4) {
            const float w0 = Wp[(size_t)(k + 0) * 128];
            const float w1 = Wp[(size_t)(k + 1) * 128];
            const float w2v = Wp[(size_t)(k + 2) * 128];
            const float w3 = Wp[(size_t)(k + 3) * 128];
#pragma unroll
            for (int i = 0; i < 16; i++) {
                const float4 v = *(const float4*)&ah[i * 128 + k];
                pacc[i] += v.x * w0;
                pacc[i] += v.y * w1;
                pacc[i] += v.z * w2v;
                pacc[i] += v.w * w3;
            }
        }
#pragma unroll
        for (int i = 0; i < 16; i++)
            Pout[(size_t)(m0 + i) * 256 + pcol] = pacc[i];
    }
}

// ---------------------------------------------------------------------------
// Action head + fused finalize (validated r15).
// ---------------------------------------------------------------------------
__global__ __launch_bounds__(256) void action_head_final(const float* __restrict__ Pa,
                                                         const int* __restrict__ ei,
                                                         const float* __restrict__ edge_attr,
                                                         const int* __restrict__ mask,
                                                         const float* __restrict__ aWe,  // 16x128
                                                         const float* __restrict__ b1,
                                                         const float* __restrict__ w2,   // 128x2
                                                         const float* __restrict__ b2,   // 2
                                                         float* __restrict__ out) {
    __shared__ int   ridx[16];
    __shared__ int   sidx[16];
    __shared__ int   eidx[16];
    __shared__ float eas[16 * 16];
    __shared__ float hid[16 * 129];
    __shared__ float o01[32];

    const int b   = blockIdx.y;
    const int j0  = blockIdx.x * 16;
    const int tid = threadIdx.x;

    if (tid < 16) {
        const int e = mask[j0 + tid];
        eidx[tid]   = e;
        ridx[tid]   = ei[e];
        sidx[tid]   = ei[En + e];
    }
    __syncthreads();
    if (tid < 64) {
        const float* eab = edge_attr + (size_t)b * En * 16;
        const int e = tid >> 2, k0 = (tid & 3) * 4;
        *(float4*)&eas[e * 16 + k0] = *(const float4*)&eab[(size_t)eidx[e] * 16 + k0];
    }
    __syncthreads();

    const int col  = tid & 127;
    const int half = tid >> 7;
    float w[16];
#pragma unroll
    for (int k = 0; k < 16; k++) w[k] = aWe[k * 128 + col];
    const float b1c = b1[col];
    const float* Pab = Pa + (size_t)b * Nn * 256;

#pragma unroll
    for (int i = 0; i < 8; i++) {
        const int e = half * 8 + i;
        float a = b1c + Pab[(size_t)ridx[e] * 256 + col]
                      + Pab[(size_t)sidx[e] * 256 + 128 + col];
        const float4 e0v = *(const float4*)&eas[e * 16 + 0];
        const float4 e1v = *(const float4*)&eas[e * 16 + 4];
        const float4 e2v = *(const float4*)&eas[e * 16 + 8];
        const float4 e3v = *(const float4*)&eas[e * 16 + 12];
        a += e0v.x * w[0];  a += e0v.y * w[1];  a += e0v.z * w[2];  a += e0v.w * w[3];
        a += e1v.x * w[4];  a += e1v.y * w[5];  a += e1v.z * w[6];  a += e1v.w * w[7];
        a += e2v.x * w[8];  a += e2v.y * w[9];  a += e2v.z * w[10]; a += e2v.w * w[11];
        a += e3v.x * w[12]; a += e3v.y * w[13]; a += e3v.z * w[14]; a += e3v.w * w[15];
        hid[e * 129 + col] = fmaxf(a, 0.f);
    }
    __syncthreads();

    const int g    = tid >> 4;
    const int lane = tid & 15;
    float o0 = 0.f, o1 = 0.f;
#pragma unroll
    for (int k = lane; k < 128; k += 16) {
        const float hv = hid[g * 129 + k];
        o0 += hv * w2[k * 2 + 0];
        o1 += hv * w2[k * 2 + 1];
    }
#pragma unroll
    for (int m = 8; m >= 1; m >>= 1) {
        o0 += __shfl_xor(o0, m);
        o1 += __shfl_xor(o1, m);
    }
    if (lane == 0) {
        o01[g * 2 + 0] = o0 + b2[0];
        o01[g * 2 + 1] = o1 + b2[1];
    }
    __syncthreads();

    if (tid < 8) {
        const float mean = 0.5f * (o01[4 * tid + 0] + o01[4 * tid + 2]);
        float l          = 0.5f * (o01[4 * tid + 1] + o01[4 * tid + 3]);
        l = fminf(fmaxf(l, -20.f), 2.f);
        constexpr int HALF = EAn / 2;          // 40000
        const int idx = b * HALF + j0 / 2 + tid;
        out[idx]             = mean;
        out[Bn * HALF + idx] = expf(l);
    }
}

// ---------------------------------------------------------------------------
extern "C" void kernel_launch(void* const* d_in, const int* in_sizes, int n_in,
                              void* d_out, int out_size, void* d_ws, size_t ws_size,
                              hipStream_t stream) {
    (void)out_size;  // unreliable (r6); geometry is compile-time.

    static const long long want[20] = {
        (long long)Bn * Nn * 64, 2LL * En, (long long)Bn * En * 16, (long long)EAn,
        144 * 128, 128, 128 * 128, 128, 192 * 128, 128,
        272 * 128, 128, 128 * 128, 128, 256 * 128, 128,
        272 * 128, 128, 128 * 2, 2};
    bool sig_ok = (n_in == 20);
    if (sig_ok)
        for (int i = 0; i < 20; i++) sig_ok = sig_ok && (in_sizes[i] == want[i]);

    const size_t PF   = (size_t)Bn * Nn * 256;   // 10,240,000
    const size_t aggF = (size_t)Bn * Nn * 128;   //  5,120,000
    const size_t hF   = (size_t)Bn * Nn * 128;   //  5,120,000
    const size_t needWords = PF + aggF + hF + 2 * En + EAn + (Nn + 16) + En + En;
    const size_t needBytes = needWords * 4;      // ~87.4 MB

    const dim3 blk(256);
    if (!sig_ok) {
        fill_sentinel<<<(OUT_N + 255) / 256, blk, 0, stream>>>((float*)d_out, 5555.f);
        return;
    }
    if (ws_size < needBytes) {
        fill_sentinel<<<(OUT_N + 255) / 256, blk, 0, stream>>>((float*)d_out, 9999.f);
        return;
    }

    const float* nodes  = (const float*)d_in[0];
    const void*  ei_raw = d_in[1];
    const float* eattr  = (const float*)d_in[2];
    const void*  mk_raw = d_in[3];
    const float* g1_mw1 = (const float*)d_in[4];
    const float* g1_mb1 = (const float*)d_in[5];
    const float* g1_mw2 = (const float*)d_in[6];
    const float* g1_mb2 = (const float*)d_in[7];
    const float* g1_uw  = (const float*)d_in[8];
    const float* g1_ub  = (const float*)d_in[9];
    const float* g2_mw1 = (const float*)d_in[10];
    const float* g2_mb1 = (const float*)d_in[11];
    const float* g2_mw2 = (const float*)d_in[12];
    const float* g2_mb2 = (const float*)d_in[13];
    const float* g2_uw  = (const float*)d_in[14];
    const float* g2_ub  = (const float*)d_in[15];
    const float* a_w1   = (const float*)d_in[16];
    const float* a_b1   = (const float*)d_in[17];
    const float* a_w2   = (const float*)d_in[18];
    const float* a_b2   = (const float*)d_in[19];

    float*        P     = (float*)d_ws;
    float*        aggH  = P + PF;
    float*        h     = aggH + aggF;
    int*          ei32  = (int*)(h + hF);
    int*          mk32  = ei32 + 2 * En;
    int*          rowst = mk32 + EAn;
    unsigned int* rsS   = (unsigned int*)(rowst + (Nn + 16));
    int*          eidS  = (int*)(rsS + En);
    int*   degi = (int*)h;                       // CSR temporaries in dead h
    int*   cur  = degi + Nn;

    const int  nbNodes = (Bn * Nn) / 16;         // 2500
    const dim3 gEdge(En / 32, Bn);               // 10000 x 4 (per-batch, r14 proven)
    const dim3 gAct(EAn / 16, Bn);               // 5000 x 4
    const size_t aggBytes = aggF * 4;

    // ---- Index decode + CSR build (batch-invariant) ----
    decode_indices<<<2500, blk, 0, stream>>>(ei_raw, mk_raw, ei32, mk32, degi, cur);
    count_deg<<<En / 256, blk, 0, stream>>>(ei32, degi);
    scan_rowstart<<<1, dim3(1024), 0, stream>>>(degi, rowst);
    fill_csr<<<En / 256, blk, 0, stream>>>(ei32, rowst, cur, rsS, eidS);

    // ---- Layer 1 ----
    precompute_P<64><<<nbNodes, blk, 0, stream>>>(nodes, g1_mw1, P);
    hipMemsetAsync(aggH, 0, aggBytes, stream);
    edge_scatter_sorted<<<gEdge, blk, 0, stream>>>(P, rsS, eidS, eattr,
                                                   g1_mw1 + 128 * 128, g1_mb1, aggH);
    // h1 + P2 fused; zeroes aggH for layer 2
    fused_node_p<64, true, true><<<nbNodes, blk, 0, stream>>>(
        nodes, aggH, g1_mw2, g1_mb2, rowst, g1_uw, g1_ub, g2_mw1, h, P);

    // ---- Layer 2 ----
    edge_scatter_sorted<<<gEdge, blk, 0, stream>>>(P, rsS, eidS, eattr,
                                                   g2_mw1 + 256 * 128, g2_mb1, aggH);
    // Pa fused; h2 never materialized
    fused_node_p<128, false, false><<<nbNodes, blk, 0, stream>>>(
        h, aggH, g2_mw2, g2_mb2, rowst, g2_uw, g2_ub, a_w1, nullptr, P);

    // ---- Action head (+ fused finalize) ----
    action_head_final<<<gAct, blk, 0, stream>>>(P, ei32, eattr, mk32,
                                                a_w1 + 256 * 128, a_b1,
                                                a_w2, a_b2, (float*)d_out);
}

// Round 19
// 717.050 us; speedup vs baseline: 1.0975x; 1.0083x over previous
//
#include <hip/hip_runtime.h>
#include <hip/hip_bf16.h>
#include <math.h>

// Problem constants
constexpr int Bn  = 4;
constexpr int Nn  = 10000;
constexpr int En  = 320000;
constexpr int EAn = 80000;
constexpr int OUT_N = 2 * Bn * (EAn / 2);   // 320000 f32: mean | std

// ---------------------------------------------------------------------------
__global__ __launch_bounds__(256) void fill_sentinel(float* out, float v) {
    const int i = blockIdx.x * 256 + threadIdx.x;
    if (i < OUT_N) out[i] = v;
}

// ---------------------------------------------------------------------------
// Index decode (validated r8) + zero degi/cur + zero aggH (absorbs the 20MB
// memset launch: aggH's first reader is layer-1 edge_scatter, later in-stream).
// ---------------------------------------------------------------------------
__global__ __launch_bounds__(256) void decode_indices(const void* __restrict__ ei_raw,
                                                      const void* __restrict__ mask_raw,
                                                      int* __restrict__ ei32,
                                                      int* __restrict__ mask32,
                                                      int* __restrict__ degi,
                                                      int* __restrict__ cur,
                                                      float* __restrict__ aggH) {
    __shared__ int is64;
    if (threadIdx.x == 0) {
        const long long* p = (const long long*)ei_raw;
        int ok = 1;
        for (int i = 0; i < 64; i++) {
            const long long v = p[i];
            if (v < 0 || v >= (long long)Nn) { ok = 0; break; }
        }
        is64 = ok;
    }
    __syncthreads();
    const int idx    = blockIdx.x * 256 + threadIdx.x;
    const int stride = gridDim.x * 256;
    if (is64) {
        for (int i = idx; i < 2 * En; i += stride)
            ei32[i] = (int)((const long long*)ei_raw)[i];
        for (int i = idx; i < EAn; i += stride)
            mask32[i] = (int)((const long long*)mask_raw)[i];
    } else {
        for (int i = idx; i < 2 * En; i += stride)
            ei32[i] = ((const int*)ei_raw)[i];
        for (int i = idx; i < EAn; i += stride)
            mask32[i] = ((const int*)mask_raw)[i];
    }
    for (int i = idx; i < Nn; i += stride) { degi[i] = 0; cur[i] = 0; }
    const float4 z = {0.f, 0.f, 0.f, 0.f};
    const size_t aggQ = (size_t)Bn * Nn * 128 / 4;   // 1.28M float4
    for (size_t i = idx; i < aggQ; i += stride)
        ((float4*)aggH)[i] = z;
}

// --------------------------- CSR construction (validated r10/r11) -----------
__global__ __launch_bounds__(256) void count_deg(const int* __restrict__ ei,
                                                 int* __restrict__ degi) {
    const int e = blockIdx.x * 256 + threadIdx.x;
    if (e < En) atomicAdd(&degi[ei[e]], 1);
}

// Exclusive scan, 1024 threads (validated r17).
__global__ __launch_bounds__(1024) void scan_rowstart(const int* __restrict__ degi,
                                                      int* __restrict__ row_start) {
    __shared__ int wsum[16];
    __shared__ int carry_s;
    const int tid  = threadIdx.x;
    const int lane = tid & 63;
    const int wv   = tid >> 6;
    if (tid == 0) { carry_s = 0; row_start[0] = 0; }
    __syncthreads();
    for (int t = 0; t < 10; t++) {             // 10*1024 = 10240 >= Nn
        const int i = t * 1024 + tid;
        int v = (i < Nn) ? degi[i] : 0;
#pragma unroll
        for (int off = 1; off < 64; off <<= 1) {
            const int x = __shfl_up(v, off);
            if (lane >= off) v += x;
        }
        if (lane == 63) wsum[wv] = v;
        __syncthreads();
        int add = 0;
        for (int w = 0; w < wv; w++) add += wsum[w];
        const int base = carry_s;
        if (i < Nn) row_start[i + 1] = base + add + v;
        __syncthreads();
        if (tid == 1023) carry_s = base + add + v;
        __syncthreads();
    }
}

// rs_sorted[pos] = (r<<16)|s  (both < 2^16); eid_sorted[pos] = original edge id.
__global__ __launch_bounds__(256) void fill_csr(const int* __restrict__ ei,
                                                const int* __restrict__ row_start,
                                                int* __restrict__ cursor,
                                                unsigned int* __restrict__ rs_sorted,
                                                int* __restrict__ eid_sorted) {
    const int e = blockIdx.x * 256 + threadIdx.x;
    if (e < En) {
        const int r   = ei[e];
        const int s   = ei[En + e];
        const int pos = row_start[r] + atomicAdd(&cursor[r], 1);
        rs_sorted[pos]  = ((unsigned int)r << 16) | (unsigned int)s;
        eid_sorted[pos] = e;
    }
}

// ---------------------------------------------------------------------------
// P = X @ [Wr | Ws] -> (B*N, 256). (r13 version — layer 1 only)
// ---------------------------------------------------------------------------
template <int KX>
__global__ __launch_bounds__(256) void precompute_P(const float* __restrict__ X,
                                                    const float* __restrict__ W,
                                                    float* __restrict__ P) {
    __shared__ float xs[16 * KX];
    const int m0  = blockIdx.x * 16;
    const int tid = threadIdx.x;

    for (int idx = tid * 4; idx < 16 * KX; idx += 1024)
        *(float4*)&xs[idx] = *(const float4*)&X[(size_t)m0 * KX + idx];
    __syncthreads();

    const int col  = tid;
    const int side = col >> 7;
    const int jj   = col & 127;
    const float* Wp = W + (size_t)(side * KX) * 128 + jj;

    float acc[16];
#pragma unroll
    for (int i = 0; i < 16; i++) acc[i] = 0.f;

    for (int k = 0; k < KX; k += 4) {
        const float w0 = Wp[(size_t)(k + 0) * 128];
        const float w1 = Wp[(size_t)(k + 1) * 128];
        const float w2 = Wp[(size_t)(k + 2) * 128];
        const float w3 = Wp[(size_t)(k + 3) * 128];
#pragma unroll
        for (int i = 0; i < 16; i++) {
            const float4 x = *(const float4*)&xs[i * KX + k];
            acc[i] += x.x * w0;
            acc[i] += x.y * w1;
            acc[i] += x.z * w2;
            acc[i] += x.w * w3;
        }
    }
#pragma unroll
    for (int i = 0; i < 16; i++) P[(size_t)(m0 + i) * 256 + col] = acc[i];
}

// ---------------------------------------------------------------------------
// Edge scatter — r14 body VERBATIM. Four-times-confirmed local optimum
// (181 µs/layer, VGPR 28, occ 86%, VALUBusy 80%). Falsified variants:
// dual-acc (r15), batch-merge (r16), run-hoisted P_r (r17). Do not touch.
// ---------------------------------------------------------------------------
__global__ __launch_bounds__(256) void edge_scatter_sorted(const float* __restrict__ P,
                                                           const unsigned int* __restrict__ rs_sorted,
                                                           const int* __restrict__ eid_sorted,
                                                           const float* __restrict__ edge_attr,
                                                           const float* __restrict__ We,  // 16x128
                                                           const float* __restrict__ b1,
                                                           float* __restrict__ aggH) {
    __shared__ int   rc[32], sc[32], ec[32];
    __shared__ float eas[32 * 16];

    const int b   = blockIdx.y;
    const int e0  = blockIdx.x * 32;
    const int tid = threadIdx.x;

    if (tid < 32) {
        const unsigned int v = rs_sorted[e0 + tid];
        rc[tid] = (int)(v >> 16);
        sc[tid] = (int)(v & 0xffffu);
        ec[tid] = eid_sorted[e0 + tid];
    }
    __syncthreads();
    {
        const float* eab = edge_attr + (size_t)b * En * 16;
        if (tid < 128) {
            const int e = tid >> 2, k0 = (tid & 3) * 4;
            *(float4*)&eas[e * 16 + k0] = *(const float4*)&eab[(size_t)ec[e] * 16 + k0];
        }
    }
    __syncthreads();

    const int col  = tid & 127;
    const int half = tid >> 7;
    const int eb   = half * 16;

    float w[16];
#pragma unroll
    for (int k = 0; k < 16; k++) w[k] = We[k * 128 + col];
    const float b1c = b1[col];

    const float* Pb   = P + (size_t)b * Nn * 256;
    float*       aggb = aggH + (size_t)b * Nn * 128;

    float run  = 0.f;
    int   curR = rc[eb];
#pragma unroll 4
    for (int i = 0; i < 16; i++) {
        const int e = eb + i;
        const int r = rc[e];
        float a = b1c + Pb[(size_t)r * 256 + col]
                      + Pb[(size_t)sc[e] * 256 + 128 + col];
        const float4 e0v = *(const float4*)&eas[e * 16 + 0];
        const float4 e1v = *(const float4*)&eas[e * 16 + 4];
        const float4 e2v = *(const float4*)&eas[e * 16 + 8];
        const float4 e3v = *(const float4*)&eas[e * 16 + 12];
        a += e0v.x * w[0];  a += e0v.y * w[1];  a += e0v.z * w[2];  a += e0v.w * w[3];
        a += e1v.x * w[4];  a += e1v.y * w[5];  a += e1v.z * w[6];  a += e1v.w * w[7];
        a += e2v.x * w[8];  a += e2v.y * w[9];  a += e2v.z * w[10]; a += e2v.w * w[11];
        a += e3v.x * w[12]; a += e3v.y * w[13]; a += e3v.z * w[14]; a += e3v.w * w[15];
        if (r != curR) {
            atomicAdd(&aggb[(size_t)curR * 128 + col], run);
            run  = 0.f;
            curR = r;
        }
        run += fmaxf(a, 0.f);
    }
    atomicAdd(&aggb[(size_t)curR * 128 + col], run);
}

// ---------------------------------------------------------------------------
// Fused node + next-stage P epilogue (validated r15).
// ---------------------------------------------------------------------------
template <int KX, bool ZERO_AGG, bool WRITE_H>
__global__ __launch_bounds__(256) void fused_node_p(const float* __restrict__ X,
                                                    float* __restrict__ aggH,
                                                    const float* __restrict__ W2,
                                                    const float* __restrict__ b2,
                                                    const int* __restrict__ row_start,
                                                    const float* __restrict__ uw,
                                                    const float* __restrict__ ub,
                                                    const float* __restrict__ Wnext, // >=256 x 128
                                                    float* __restrict__ Hout,
                                                    float* __restrict__ Pout) {
    __shared__ float ah[16 * 128];
    __shared__ float ag[16 * 128];
    __shared__ float xs[16 * KX];
    __shared__ float dg[16];

    const int m0  = blockIdx.x * 16;     // Nn % 16 == 0 -> never straddles batch
    const int tid = threadIdx.x;

    if (tid < 16) {
        const int row = m0 + tid;
        const int nl  = row - (row / Nn) * Nn;
        dg[tid] = (float)(row_start[nl + 1] - row_start[nl]);
    }
    for (int idx = tid * 4; idx < 16 * 128; idx += 1024)
        *(float4*)&ah[idx] = *(const float4*)&aggH[(size_t)m0 * 128 + idx];
    for (int idx = tid * 4; idx < 16 * KX; idx += 1024)
        *(float4*)&xs[idx] = *(const float4*)&X[(size_t)m0 * KX + idx];
    __syncthreads();

    if (ZERO_AGG) {  // own rows only; consumed into LDS above
        const float4 z = {0.f, 0.f, 0.f, 0.f};
        for (int idx = tid * 4; idx < 16 * 128; idx += 1024)
            *(float4*)&aggH[(size_t)m0 * 128 + idx] = z;
    }

    const int col  = tid & 127;
    const int half = tid >> 7;

    {   // Phase A: ag = ah @ W2 + dg*b2
        const float b2c = b2[col];
        float acc[8];
#pragma unroll
        for (int i = 0; i < 8; i++) acc[i] = dg[half * 8 + i] * b2c;
        for (int k = 0; k < 128; k += 4) {
            const float w0 = W2[(k + 0) * 128 + col];
            const float w1 = W2[(k + 1) * 128 + col];
            const float w2v = W2[(k + 2) * 128 + col];
            const float w3 = W2[(k + 3) * 128 + col];
#pragma unroll
            for (int i = 0; i < 8; i++) {
                const float4 v = *(const float4*)&ah[(half * 8 + i) * 128 + k];
                acc[i] += v.x * w0;
                acc[i] += v.y * w1;
                acc[i] += v.z * w2v;
                acc[i] += v.w * w3;
            }
        }
#pragma unroll
        for (int i = 0; i < 8; i++) ag[(half * 8 + i) * 128 + col] = acc[i];
    }
    __syncthreads();

    // Phase B: h' = relu([X | ag] @ uw + ub) -> ah (reuse) [+ global]
    {
        float acc[8];
#pragma unroll
        for (int i = 0; i < 8; i++) acc[i] = ub[col];
        for (int k = 0; k < KX; k += 4) {
            const float w0 = uw[(size_t)(k + 0) * 128 + col];
            const float w1 = uw[(size_t)(k + 1) * 128 + col];
            const float w2v = uw[(size_t)(k + 2) * 128 + col];
            const float w3 = uw[(size_t)(k + 3) * 128 + col];
#pragma unroll
            for (int i = 0; i < 8; i++) {
                const float4 v = *(const float4*)&xs[(half * 8 + i) * KX + k];
                acc[i] += v.x * w0;
                acc[i] += v.y * w1;
                acc[i] += v.z * w2v;
                acc[i] += v.w * w3;
            }
        }
        for (int k = 0; k < 128; k += 4) {
            const float w0 = uw[(size_t)(KX + k + 0) * 128 + col];
            const float w1 = uw[(size_t)(KX + k + 1) * 128 + col];
            const float w2v = uw[(size_t)(KX + k + 2) * 128 + col];
            const float w3 = uw[(size_t)(KX + k + 3) * 128 + col];
#pragma unroll
            for (int i = 0; i < 8; i++) {
                const float4 v = *(const float4*)&ag[(half * 8 + i) * 128 + k];
                acc[i] += v.x * w0;
                acc[i] += v.y * w1;
                acc[i] += v.z * w2v;
                acc[i] += v.w * w3;
            }
        }
#pragma unroll
        for (int i = 0; i < 8; i++) {
            const float hv = fmaxf(acc[i], 0.f);
            ah[(half * 8 + i) * 128 + col] = hv;
            if (WRITE_H)
                Hout[(size_t)(m0 + half * 8 + i) * 128 + col] = hv;
        }
    }
    __syncthreads();

    // Epilogue: Pout = h' @ [Wnext_r | Wnext_s]  (thread = 1 of 256 cols)
    {
        const int pcol = tid;
        const int side = pcol >> 7;
        const int jj   = pcol & 127;
        const float* Wp = Wnext + (size_t)(side * 128) * 128 + jj;
        float pacc[16];
#pragma unroll
        for (int i = 0; i < 16; i++) pacc[i] = 0.f;
        for (int k = 0; k < 128; k += 4) {
            const float w0 = Wp[(size_t)(k + 0) * 128];
            const float w1 = Wp[(size_t)(k + 1) * 128];
            const float w2v = Wp[(size_t)(k + 2) * 128];
            const float w3 = Wp[(size_t)(k + 3) * 128];
#pragma unroll
            for (int i = 0; i < 16; i++) {
                const float4 v = *(const float4*)&ah[i * 128 + k];
                pacc[i] += v.x * w0;
                pacc[i] += v.y * w1;
                pacc[i] += v.z * w2v;
                pacc[i] += v.w * w3;
            }
        }
#pragma unroll
        for (int i = 0; i < 16; i++)
            Pout[(size_t)(m0 + i) * 256 + pcol] = pacc[i];
    }
}

// ---------------------------------------------------------------------------
// Action head + fused finalize (validated r15).
// ---------------------------------------------------------------------------
__global__ __launch_bounds__(256) void action_head_final(const float* __restrict__ Pa,
                                                         const int* __restrict__ ei,
                                                         const float* __restrict__ edge_attr,
                                                         const int* __restrict__ mask,
                                                         const float* __restrict__ aWe,  // 16x128
                                                         const float* __restrict__ b1,
                                                         const float* __restrict__ w2,   // 128x2
                                                         const float* __restrict__ b2,   // 2
                                                         float* __restrict__ out) {
    __shared__ int   ridx[16];
    __shared__ int   sidx[16];
    __shared__ int   eidx[16];
    __shared__ float eas[16 * 16];
    __shared__ float hid[16 * 129];
    __shared__ float o01[32];

    const int b   = blockIdx.y;
    const int j0  = blockIdx.x * 16;
    const int tid = threadIdx.x;

    if (tid < 16) {
        const int e = mask[j0 + tid];
        eidx[tid]   = e;
        ridx[tid]   = ei[e];
        sidx[tid]   = ei[En + e];
    }
    __syncthreads();
    if (tid < 64) {
        const float* eab = edge_attr + (size_t)b * En * 16;
        const int e = tid >> 2, k0 = (tid & 3) * 4;
        *(float4*)&eas[e * 16 + k0] = *(const float4*)&eab[(size_t)eidx[e] * 16 + k0];
    }
    __syncthreads();

    const int col  = tid & 127;
    const int half = tid >> 7;
    float w[16];
#pragma unroll
    for (int k = 0; k < 16; k++) w[k] = aWe[k * 128 + col];
    const float b1c = b1[col];
    const float* Pab = Pa + (size_t)b * Nn * 256;

#pragma unroll
    for (int i = 0; i < 8; i++) {
        const int e = half * 8 + i;
        float a = b1c + Pab[(size_t)ridx[e] * 256 + col]
                      + Pab[(size_t)sidx[e] * 256 + 128 + col];
        const float4 e0v = *(const float4*)&eas[e * 16 + 0];
        const float4 e1v = *(const float4*)&eas[e * 16 + 4];
        const float4 e2v = *(const float4*)&eas[e * 16 + 8];
        const float4 e3v = *(const float4*)&eas[e * 16 + 12];
        a += e0v.x * w[0];  a += e0v.y * w[1];  a += e0v.z * w[2];  a += e0v.w * w[3];
        a += e1v.x * w[4];  a += e1v.y * w[5];  a += e1v.z * w[6];  a += e1v.w * w[7];
        a += e2v.x * w[8];  a += e2v.y * w[9];  a += e2v.z * w[10]; a += e2v.w * w[11];
        a += e3v.x * w[12]; a += e3v.y * w[13]; a += e3v.z * w[14]; a += e3v.w * w[15];
        hid[e * 129 + col] = fmaxf(a, 0.f);
    }
    __syncthreads();

    const int g    = tid >> 4;
    const int lane = tid & 15;
    float o0 = 0.f, o1 = 0.f;
#pragma unroll
    for (int k = lane; k < 128; k += 16) {
        const float hv = hid[g * 129 + k];
        o0 += hv * w2[k * 2 + 0];
        o1 += hv * w2[k * 2 + 1];
    }
#pragma unroll
    for (int m = 8; m >= 1; m >>= 1) {
        o0 += __shfl_xor(o0, m);
        o1 += __shfl_xor(o1, m);
    }
    if (lane == 0) {
        o01[g * 2 + 0] = o0 + b2[0];
        o01[g * 2 + 1] = o1 + b2[1];
    }
    __syncthreads();

    if (tid < 8) {
        const float mean = 0.5f * (o01[4 * tid + 0] + o01[4 * tid + 2]);
        float l          = 0.5f * (o01[4 * tid + 1] + o01[4 * tid + 3]);
        l = fminf(fmaxf(l, -20.f), 2.f);
        constexpr int HALF = EAn / 2;          // 40000
        const int idx = b * HALF + j0 / 2 + tid;
        out[idx]             = mean;
        out[Bn * HALF + idx] = expf(l);
    }
}

// ---------------------------------------------------------------------------
extern "C" void kernel_launch(void* const* d_in, const int* in_sizes, int n_in,
                              void* d_out, int out_size, void* d_ws, size_t ws_size,
                              hipStream_t stream) {
    (void)out_size;  // unreliable (r6); geometry is compile-time.

    static const long long want[20] = {
        (long long)Bn * Nn * 64, 2LL * En, (long long)Bn * En * 16, (long long)EAn,
        144 * 128, 128, 128 * 128, 128, 192 * 128, 128,
        272 * 128, 128, 128 * 128, 128, 256 * 128, 128,
        272 * 128, 128, 128 * 2, 2};
    bool sig_ok = (n_in == 20);
    if (sig_ok)
        for (int i = 0; i < 20; i++) sig_ok = sig_ok && (in_sizes[i] == want[i]);

    const size_t PF   = (size_t)Bn * Nn * 256;   // 10,240,000
    const size_t aggF = (size_t)Bn * Nn * 128;   //  5,120,000
    const size_t hF   = (size_t)Bn * Nn * 128;   //  5,120,000
    const size_t needWords = PF + aggF + hF + 2 * En + EAn + (Nn + 16) + En + En;
    const size_t needBytes = needWords * 4;      // ~87.4 MB

    const dim3 blk(256);
    if (!sig_ok) {
        fill_sentinel<<<(OUT_N + 255) / 256, blk, 0, stream>>>((float*)d_out, 5555.f);
        return;
    }
    if (ws_size < needBytes) {
        fill_sentinel<<<(OUT_N + 255) / 256, blk, 0, stream>>>((float*)d_out, 9999.f);
        return;
    }

    const float* nodes  = (const float*)d_in[0];
    const void*  ei_raw = d_in[1];
    const float* eattr  = (const float*)d_in[2];
    const void*  mk_raw = d_in[3];
    const float* g1_mw1 = (const float*)d_in[4];
    const float* g1_mb1 = (const float*)d_in[5];
    const float* g1_mw2 = (const float*)d_in[6];
    const float* g1_mb2 = (const float*)d_in[7];
    const float* g1_uw  = (const float*)d_in[8];
    const float* g1_ub  = (const float*)d_in[9];
    const float* g2_mw1 = (const float*)d_in[10];
    const float* g2_mb1 = (const float*)d_in[11];
    const float* g2_mw2 = (const float*)d_in[12];
    const float* g2_mb2 = (const float*)d_in[13];
    const float* g2_uw  = (const float*)d_in[14];
    const float* g2_ub  = (const float*)d_in[15];
    const float* a_w1   = (const float*)d_in[16];
    const float* a_b1   = (const float*)d_in[17];
    const float* a_w2   = (const float*)d_in[18];
    const float* a_b2   = (const float*)d_in[19];

    float*        P     = (float*)d_ws;
    float*        aggH  = P + PF;
    float*        h     = aggH + aggF;
    int*          ei32  = (int*)(h + hF);
    int*          mk32  = ei32 + 2 * En;
    int*          rowst = mk32 + EAn;
    unsigned int* rsS   = (unsigned int*)(rowst + (Nn + 16));
    int*          eidS  = (int*)(rsS + En);
    int*   degi = (int*)h;                       // CSR temporaries in dead h
    int*   cur  = degi + Nn;

    const int  nbNodes = (Bn * Nn) / 16;         // 2500
    const dim3 gEdge(En / 32, Bn);               // 10000 x 4 (per-batch, r14 proven)
    const dim3 gAct(EAn / 16, Bn);               // 5000 x 4

    // ---- Index decode + CSR build (batch-invariant); decode also zeros aggH ----
    decode_indices<<<2500, blk, 0, stream>>>(ei_raw, mk_raw, ei32, mk32, degi, cur, aggH);
    count_deg<<<En / 256, blk, 0, stream>>>(ei32, degi);
    scan_rowstart<<<1, dim3(1024), 0, stream>>>(degi, rowst);
    fill_csr<<<En / 256, blk, 0, stream>>>(ei32, rowst, cur, rsS, eidS);

    // ---- Layer 1 ----
    precompute_P<64><<<nbNodes, blk, 0, stream>>>(nodes, g1_mw1, P);
    edge_scatter_sorted<<<gEdge, blk, 0, stream>>>(P, rsS, eidS, eattr,
                                                   g1_mw1 + 128 * 128, g1_mb1, aggH);
    // h1 + P2 fused; zeroes aggH for layer 2
    fused_node_p<64, true, true><<<nbNodes, blk, 0, stream>>>(
        nodes, aggH, g1_mw2, g1_mb2, rowst, g1_uw, g1_ub, g2_mw1, h, P);

    // ---- Layer 2 ----
    edge_scatter_sorted<<<gEdge, blk, 0, stream>>>(P, rsS, eidS, eattr,
                                                   g2_mw1 + 256 * 128, g2_mb1, aggH);
    // Pa fused; h2 never materialized
    fused_node_p<128, false, false><<<nbNodes, blk, 0, stream>>>(
        h, aggH, g2_mw2, g2_mb2, rowst, g2_uw, g2_ub, a_w1, nullptr, P);

    // ---- Action head (+ fused finalize) ----
    action_head_final<<<gAct, blk, 0, stream>>>(P, ei32, eattr, mk32,
                                                a_w1 + 256 * 128, a_b1,
                                                a_w2, a_b2, (float*)d_out);
}